// Round 2
// baseline (510.558 us; speedup 1.0000x reference)
//
#include <hip/hip_runtime.h>
#include <cstddef>

#define Bn 128
#define Pn 8732
#define Cn 21
#define On 16

__device__ __forceinline__ void argmax_combine(float& v, int& p, float v2, int p2) {
  if (v2 > v || (v2 == v && p2 < p)) { v = v2; p = p2; }
}

// ---------------------------------------------------------------------------
// Kernel 1: SSD matching. One 1024-thread block per image. Packed byte/prior:
//   bits 0..3 = bti (matched truth index), bit 4 = pos flag.
// Also zero-initializes num_pos and acc (runs before their consumers).
// ---------------------------------------------------------------------------
__global__ __launch_bounds__(1024) void match_kernel(
    const float* __restrict__ dbox, const float* __restrict__ targets,
    unsigned char* __restrict__ match,
    int* __restrict__ num_pos, float* __restrict__ acc) {
  const int b = blockIdx.x;
  const int tid = threadIdx.x;
  const int wave = tid >> 6, lane = tid & 63;
  __shared__ float s_t[On * 5];
  __shared__ float s_area[On];
  __shared__ int s_bp[On];
  __shared__ float s_wv[On][16];
  __shared__ int s_wp[On][16];

  if (tid == 0) num_pos[b] = 0;
  if (b == 0 && tid < 32) acc[tid] = 0.0f;

  if (tid < On * 5) s_t[tid] = targets[(size_t)b * On * 5 + tid];
  __syncthreads();
  if (tid < On)
    s_area[tid] = (s_t[tid*5+2] - s_t[tid*5+0]) * (s_t[tid*5+3] - s_t[tid*5+1]);
  __syncthreads();

  // Pass 1: per-truth argmax over priors (first occurrence of max).
  float bestv[On]; int bestp[On];
  #pragma unroll
  for (int j = 0; j < On; j++) { bestv[j] = -1.0f; bestp[j] = 0x7fffffff; }

  for (int p = tid; p < Pn; p += 1024) {
    float4 d = ((const float4*)dbox)[p];
    float px1 = d.x - d.z * 0.5f, py1 = d.y - d.w * 0.5f;
    float px2 = d.x + d.z * 0.5f, py2 = d.y + d.w * 0.5f;
    float ap = d.z * d.w;
    #pragma unroll
    for (int j = 0; j < On; j++) {
      float lx = fmaxf(s_t[j*5+0], px1);
      float ly = fmaxf(s_t[j*5+1], py1);
      float rx = fminf(s_t[j*5+2], px2);
      float ry = fminf(s_t[j*5+3], py2);
      float w = fmaxf(rx - lx, 0.0f), h = fmaxf(ry - ly, 0.0f);
      float inter = w * h;
      float ov = inter / (s_area[j] + ap - inter);
      if (ov > bestv[j]) { bestv[j] = ov; bestp[j] = p; }  // strict > => smallest p among maxima
    }
  }

  #pragma unroll
  for (int j = 0; j < On; j++) {
    float v = bestv[j]; int p = bestp[j];
    #pragma unroll
    for (int off = 32; off; off >>= 1) {
      float v2 = __shfl_down(v, off);
      int p2 = __shfl_down(p, off);
      argmax_combine(v, p, v2, p2);
    }
    if (lane == 0) { s_wv[j][wave] = v; s_wp[j][wave] = p; }
  }
  __syncthreads();
  if (tid < On) {
    float v = s_wv[tid][0]; int p = s_wp[tid][0];
    #pragma unroll
    for (int w = 1; w < 16; w++) argmax_combine(v, p, s_wv[tid][w], s_wp[tid][w]);
    s_bp[tid] = p;
  }
  __syncthreads();

  // Pass 2: per-prior best truth (first max over j), apply forced matches.
  for (int p = tid; p < Pn; p += 1024) {
    float4 d = ((const float4*)dbox)[p];
    float px1 = d.x - d.z * 0.5f, py1 = d.y - d.w * 0.5f;
    float px2 = d.x + d.z * 0.5f, py2 = d.y + d.w * 0.5f;
    float ap = d.z * d.w;
    float mv = -1.0f; int mj = 0;
    #pragma unroll
    for (int j = 0; j < On; j++) {
      float lx = fmaxf(s_t[j*5+0], px1);
      float ly = fmaxf(s_t[j*5+1], py1);
      float rx = fminf(s_t[j*5+2], px2);
      float ry = fminf(s_t[j*5+3], py2);
      float w = fmaxf(rx - lx, 0.0f), h = fmaxf(ry - ly, 0.0f);
      float inter = w * h;
      float ov = inter / (s_area[j] + ap - inter);
      if (ov > mv) { mv = ov; mj = j; }  // first max (jnp.argmax axis=0)
    }
    int forced = -1;
    #pragma unroll
    for (int j = 0; j < On; j++) if (s_bp[j] == p) forced = j;  // last j wins
    int bti, pos;
    if (forced >= 0) { bti = forced; pos = 1; }
    else { bti = mj; pos = (mv >= 0.5f) ? 1 : 0; }
    match[(size_t)b * Pn + p] = (unsigned char)(bti | (pos << 4));
  }
}

// ---------------------------------------------------------------------------
// Kernel 2: per-prior CE + loc smooth-L1. Per-WAVE LDS staging, NO barriers:
// each wave float4-loads its own 64 priors' conf rows into a private LDS
// slice, then computes. Per-wave shuffle reduce -> atomics into 8 replicas.
// ---------------------------------------------------------------------------
__global__ __launch_bounds__(256) void loss_kernel(
    const float* __restrict__ loc_data, const float* __restrict__ conf_data,
    const float* __restrict__ dbox, const float* __restrict__ targets,
    const unsigned char* __restrict__ match,
    float* __restrict__ ce_neg, int* __restrict__ num_pos,
    float* __restrict__ acc) {
  const int b = blockIdx.y;
  const int wave = threadIdx.x >> 6, lane = threadIdx.x & 63;
  __shared__ float lds[4][64 * Cn];

  const int row0 = blockIdx.x * 256 + wave * 64;       // first prior of this wave
  const int rows = min(64, Pn - row0);                 // Pn%4==0 -> rows%4==0
  if (rows <= 0) return;

  // Cooperative per-wave staging: rows*21 floats, 16B-aligned (row0*84 % 16 == 0).
  {
    const float4* src = (const float4*)(conf_data + ((size_t)b * Pn + row0) * Cn);
    float4* dst = (float4*)lds[wave];
    const int n4 = rows * Cn / 4;
    for (int i = lane; i < n4; i += 64) dst[i] = src[i];
  }
  // No __syncthreads: producer == consumer wave; compiler inserts waitcnts.

  float my_ce_pos = 0.0f, my_loc = 0.0f; int my_pos = 0;
  const int p = row0 + lane;
  if (lane < rows) {
    const float* x = lds[wave] + lane * Cn;
    float m = x[0];
    #pragma unroll
    for (int i = 1; i < Cn; i++) m = fmaxf(m, x[i]);
    float s = 0.0f;
    #pragma unroll
    for (int i = 0; i < Cn; i++) s += expf(x[i] - m);
    float lse = m + logf(s);

    unsigned char mb = match[(size_t)b * Pn + p];
    int pos = (mb >> 4) & 1;
    int bti = mb & 15;
    const float* t = targets + ((size_t)b * On + bti) * 5;
    int c = pos ? ((int)t[4] + 1) : 0;
    float ce = lse - x[c];
    ce_neg[(size_t)b * Pn + p] = pos ? 0.0f : ce;

    if (pos) {
      my_ce_pos = ce;
      my_pos = 1;
      float4 d = ((const float4*)dbox)[p];
      float mx1 = t[0], my1 = t[1], mx2 = t[2], my2 = t[3];
      float g0 = ((mx1 + mx2) * 0.5f - d.x) / (0.1f * d.z);
      float g1 = ((my1 + my2) * 0.5f - d.y) / (0.1f * d.w);
      float g2 = logf((mx2 - mx1) / d.z) / 0.2f;
      float g3 = logf((my2 - my1) / d.w) / 0.2f;
      float4 ld = ((const float4*)loc_data)[(size_t)b * Pn + p];
      float g[4] = {g0, g1, g2, g3};
      float l[4] = {ld.x, ld.y, ld.z, ld.w};
      #pragma unroll
      for (int i = 0; i < 4; i++) {
        float ad = fabsf(l[i] - g[i]);
        my_loc += (ad < 1.0f) ? 0.5f * ad * ad : ad - 0.5f;
      }
    }
  }

  #pragma unroll
  for (int off = 32; off; off >>= 1) {
    my_ce_pos += __shfl_down(my_ce_pos, off);
    my_loc    += __shfl_down(my_loc, off);
    my_pos    += __shfl_down(my_pos, off);
  }
  if (lane == 0) {
    const int r = (blockIdx.x + blockIdx.y + wave) & 7;   // spread contention
    atomicAdd(&acc[r * 4 + 0], my_loc);
    atomicAdd(&acc[r * 4 + 1], my_ce_pos);
    if (my_pos) atomicAdd(&num_pos[b], my_pos);
  }
}

// ---------------------------------------------------------------------------
// Kernel 3: per-image hard-negative top-k sum via exact MSB radix select.
// 1024 threads, per-wave private histograms. ce_neg >= 0 so float ordering ==
// uint ordering. sum = sum(v>T) + (k - cnt_gt)*T  (replicates stable top-k).
// ---------------------------------------------------------------------------
__global__ __launch_bounds__(1024) void select_kernel(
    const float* __restrict__ ce_neg, const int* __restrict__ num_pos,
    float* __restrict__ acc) {
  const int b = blockIdx.x;
  const int tid = threadIdx.x;
  const int wave = tid >> 6, lane = tid & 63;
  const int k = min(num_pos[b] * 3, Pn);
  const unsigned* v = (const unsigned*)(ce_neg + (size_t)b * Pn);
  __shared__ unsigned hist[16][256];
  __shared__ unsigned s_prefix;
  __shared__ int s_kk;
  __shared__ float rs[16];
  __shared__ int rc[16];

  unsigned prefix = 0, mask = 0;
  int kk = k;
  if (k > 0) {
    for (int shift = 24; shift >= 0; shift -= 8) {
      #pragma unroll
      for (int j = 0; j < 4; j++) hist[wave][lane * 4 + j] = 0;
      __syncthreads();
      for (int i = tid; i < Pn; i += 1024) {
        unsigned u = v[i];
        if ((u & mask) == prefix) atomicAdd(&hist[wave][(u >> shift) & 255u], 1u);
      }
      __syncthreads();
      if (tid < 256) {
        unsigned c = 0;
        #pragma unroll
        for (int w = 0; w < 16; w++) c += hist[w][tid];
        hist[0][tid] = c;
      }
      __syncthreads();
      if (tid == 0) {
        int cum = 0, chosen = 0;
        for (int bin = 255; bin >= 0; bin--) {
          int c = (int)hist[0][bin];
          if (cum + c >= kk) { chosen = bin; break; }
          cum += c;
        }
        s_prefix = prefix | ((unsigned)chosen << shift);
        s_kk = kk - cum;
      }
      __syncthreads();
      prefix = s_prefix; kk = s_kk;
      mask |= 255u << shift;
      __syncthreads();
    }
  }
  float T = __uint_as_float(prefix);

  float sum_gt = 0.0f; int cnt_gt = 0;
  if (k > 0) {
    const float* vf = ce_neg + (size_t)b * Pn;
    for (int i = tid; i < Pn; i += 1024) {
      float x = vf[i];
      if (x > T) { sum_gt += x; cnt_gt++; }
    }
  }
  #pragma unroll
  for (int off = 32; off; off >>= 1) {
    sum_gt += __shfl_down(sum_gt, off);
    cnt_gt += __shfl_down(cnt_gt, off);
  }
  if (lane == 0) { rs[wave] = sum_gt; rc[wave] = cnt_gt; }
  __syncthreads();
  if (tid == 0) {
    float s = 0.0f; int c = 0;
    #pragma unroll
    for (int w = 0; w < 16; w++) { s += rs[w]; c += rc[w]; }
    float sel = s + (float)(k - c) * T;
    atomicAdd(&acc[((b & 7) * 4) + 2], sel);
  }
}

__global__ __launch_bounds__(64) void finalize_kernel(
    const int* __restrict__ num_pos, const float* __restrict__ acc,
    float* __restrict__ out) {
  const int tid = threadIdx.x;
  int n = num_pos[tid] + num_pos[tid + 64];
  #pragma unroll
  for (int off = 32; off; off >>= 1) n += __shfl_down(n, off);
  if (tid == 0) {
    float ll = 0.0f, lc = 0.0f;
    #pragma unroll
    for (int r = 0; r < 8; r++) {
      ll += acc[r * 4 + 0];
      lc += acc[r * 4 + 1] + acc[r * 4 + 2];
    }
    float fN = (float)n;
    out[0] = ll / fN;
    out[1] = lc / fN;
  }
}

extern "C" void kernel_launch(void* const* d_in, const int* in_sizes, int n_in,
                              void* d_out, int out_size, void* d_ws, size_t ws_size,
                              hipStream_t stream) {
  const float* loc_data  = (const float*)d_in[0];
  const float* conf_data = (const float*)d_in[1];
  const float* dbox      = (const float*)d_in[2];
  const float* targets   = (const float*)d_in[3];
  float* out = (float*)d_out;

  char* ws = (char*)d_ws;
  float* ce_neg = (float*)ws;                                        // B*P floats
  unsigned char* match = (unsigned char*)(ws + (size_t)Bn * Pn * 4); // B*P bytes
  int* num_pos = (int*)(ws + (size_t)Bn * Pn * 5);                   // 128 ints
  float* acc = (float*)(ws + (size_t)Bn * Pn * 5 + 512);             // 32 floats

  match_kernel<<<Bn, 1024, 0, stream>>>(dbox, targets, match, num_pos, acc);
  dim3 gB((Pn + 255) / 256, Bn);
  loss_kernel<<<gB, 256, 0, stream>>>(loc_data, conf_data, dbox, targets, match,
                                      ce_neg, num_pos, acc);
  select_kernel<<<Bn, 1024, 0, stream>>>(ce_neg, num_pos, acc);
  finalize_kernel<<<1, 64, 0, stream>>>(num_pos, acc, out);
}

// Round 3
// 282.248 us; speedup vs baseline: 1.8089x; 1.8089x over previous
//
#include <hip/hip_runtime.h>
#include <cstddef>

#define Bn 128
#define Pn 8732
#define Cn 21
#define On 16

// conf rows are 84 B apart -> only 4B-aligned; this type makes the compiler
// emit global_load_dwordx4 with align-4 semantics (supported on gfx950).
typedef float float4a __attribute__((ext_vector_type(4), aligned(4)));

__device__ __forceinline__ void argmax_combine(float& v, int& p, float v2, int p2) {
  if (v2 > v || (v2 == v && p2 < p)) { v = v2; p = p2; }
}

// ---------------------------------------------------------------------------
// One block per image: match (LDS) -> CE/loc loss (conf direct to VGPR) ->
// exact radix top-k of ce_neg (LDS) -> per-block partials to blk_res[b].
// ---------------------------------------------------------------------------
__global__ __launch_bounds__(1024) void fused_kernel(
    const float* __restrict__ loc_data, const float* __restrict__ conf_data,
    const float* __restrict__ dbox, const float* __restrict__ targets,
    float4* __restrict__ blk_res) {
  const int b = blockIdx.x;
  const int tid = threadIdx.x;
  const int wave = tid >> 6, lane = tid & 63;

  __shared__ float s_ce[Pn];            // phase 0: bto ; phase 1+: ce_neg
  __shared__ unsigned char s_bti[Pn];   // matched truth index per prior
  __shared__ float s_t[On * 5];
  __shared__ float s_area[On];
  __shared__ int s_bp[On];
  __shared__ float s_wv[On][16];
  __shared__ int s_wp[On][16];
  __shared__ unsigned hist[16][256];
  __shared__ float s_red[3][16];
  __shared__ int s_redi[16];
  __shared__ int s_np;
  __shared__ unsigned s_prefix;
  __shared__ int s_kk;

  if (tid < On * 5) s_t[tid] = targets[(size_t)b * On * 5 + tid];
  __syncthreads();
  if (tid < On)
    s_area[tid] = (s_t[tid*5+2] - s_t[tid*5+0]) * (s_t[tid*5+3] - s_t[tid*5+1]);
  __syncthreads();

  // ---- Phase 0: single IoU pass: per-prior best truth AND per-truth best prior
  float bestv[On]; int bestp[On];
  #pragma unroll
  for (int j = 0; j < On; j++) { bestv[j] = -1.0f; bestp[j] = 0x7fffffff; }

  for (int p = tid; p < Pn; p += 1024) {
    float4 d = ((const float4*)dbox)[p];
    float px1 = d.x - d.z * 0.5f, py1 = d.y - d.w * 0.5f;
    float px2 = d.x + d.z * 0.5f, py2 = d.y + d.w * 0.5f;
    float ap = d.z * d.w;
    float mv = -1.0f; int mj = 0;
    #pragma unroll
    for (int j = 0; j < On; j++) {
      float lx = fmaxf(s_t[j*5+0], px1);
      float ly = fmaxf(s_t[j*5+1], py1);
      float rx = fminf(s_t[j*5+2], px2);
      float ry = fminf(s_t[j*5+3], py2);
      float w = fmaxf(rx - lx, 0.0f), h = fmaxf(ry - ly, 0.0f);
      float inter = w * h;
      float ov = inter / (s_area[j] + ap - inter);
      if (ov > bestv[j]) { bestv[j] = ov; bestp[j] = p; }  // strict > : smallest p kept
      if (ov > mv) { mv = ov; mj = j; }                    // strict > : first max over j
    }
    s_ce[p] = mv;                    // bto
    s_bti[p] = (unsigned char)mj;    // bti
  }

  #pragma unroll
  for (int j = 0; j < On; j++) {
    float v = bestv[j]; int p = bestp[j];
    #pragma unroll
    for (int off = 32; off; off >>= 1) {
      float v2 = __shfl_down(v, off);
      int p2 = __shfl_down(p, off);
      argmax_combine(v, p, v2, p2);
    }
    if (lane == 0) { s_wv[j][wave] = v; s_wp[j][wave] = p; }
  }
  __syncthreads();
  if (tid < On) {
    float v = s_wv[tid][0]; int p = s_wp[tid][0];
    #pragma unroll
    for (int w = 1; w < 16; w++) argmax_combine(v, p, s_wv[tid][w], s_wp[tid][w]);
    s_bp[tid] = p;
  }
  __syncthreads();
  if (tid == 0) {
    #pragma unroll
    for (int j = 0; j < On; j++) {          // sequential: last j wins (torch loop)
      int p = s_bp[j];
      s_bti[p] = (unsigned char)j;
      s_ce[p] = 2.0f;                       // bto forced
    }
  }
  __syncthreads();

  // ---- Phase 1: CE per prior (conf row direct to VGPRs), loc loss for positives
  float my_loc = 0.0f, my_cep = 0.0f; int my_np = 0;
  for (int p = tid; p < Pn; p += 1024) {
    const float* row = conf_data + ((size_t)b * Pn + p) * Cn;
    const float4a* r4 = (const float4a*)row;
    float4a a0 = r4[0], a1 = r4[1], a2 = r4[2], a3 = r4[3], a4 = r4[4];
    float x20 = row[20];

    float m = a0.x;
    m = fmaxf(m, a0.y); m = fmaxf(m, a0.z); m = fmaxf(m, a0.w);
    m = fmaxf(m, a1.x); m = fmaxf(m, a1.y); m = fmaxf(m, a1.z); m = fmaxf(m, a1.w);
    m = fmaxf(m, a2.x); m = fmaxf(m, a2.y); m = fmaxf(m, a2.z); m = fmaxf(m, a2.w);
    m = fmaxf(m, a3.x); m = fmaxf(m, a3.y); m = fmaxf(m, a3.z); m = fmaxf(m, a3.w);
    m = fmaxf(m, a4.x); m = fmaxf(m, a4.y); m = fmaxf(m, a4.z); m = fmaxf(m, a4.w);
    m = fmaxf(m, x20);
    float s = expf(a0.x - m) + expf(a0.y - m) + expf(a0.z - m) + expf(a0.w - m)
            + expf(a1.x - m) + expf(a1.y - m) + expf(a1.z - m) + expf(a1.w - m)
            + expf(a2.x - m) + expf(a2.y - m) + expf(a2.z - m) + expf(a2.w - m)
            + expf(a3.x - m) + expf(a3.y - m) + expf(a3.z - m) + expf(a3.w - m)
            + expf(a4.x - m) + expf(a4.y - m) + expf(a4.z - m) + expf(a4.w - m)
            + expf(x20 - m);
    float lse = m + logf(s);
    float ce0 = lse - a0.x;              // CE with class 0 (negatives)

    float bto = s_ce[p];
    int pos = (bto >= 0.5f) ? 1 : 0;
    s_ce[p] = pos ? 0.0f : ce0;          // becomes ce_neg (same thread, same slot)

    if (pos) {
      my_np++;
      int bti = s_bti[p];
      const float* t = &s_t[bti * 5];
      int c = (int)t[4] + 1;             // label in [0,19] -> c in [1,20]
      my_cep += lse - row[c];            // rare divergent global load
      float4 d = ((const float4*)dbox)[p];
      float mx1 = t[0], my1 = t[1], mx2 = t[2], my2 = t[3];
      float g0 = ((mx1 + mx2) * 0.5f - d.x) / (0.1f * d.z);
      float g1 = ((my1 + my2) * 0.5f - d.y) / (0.1f * d.w);
      float g2 = logf((mx2 - mx1) / d.z) / 0.2f;
      float g3 = logf((my2 - my1) / d.w) / 0.2f;
      float4 ld = ((const float4*)loc_data)[(size_t)b * Pn + p];
      float g[4] = {g0, g1, g2, g3};
      float l[4] = {ld.x, ld.y, ld.z, ld.w};
      #pragma unroll
      for (int i = 0; i < 4; i++) {
        float ad = fabsf(l[i] - g[i]);
        my_loc += (ad < 1.0f) ? 0.5f * ad * ad : ad - 0.5f;
      }
    }
  }

  #pragma unroll
  for (int off = 32; off; off >>= 1) {
    my_loc  += __shfl_down(my_loc, off);
    my_cep  += __shfl_down(my_cep, off);
    my_np   += __shfl_down(my_np, off);
  }
  if (lane == 0) { s_red[0][wave] = my_loc; s_red[1][wave] = my_cep; s_redi[wave] = my_np; }
  __syncthreads();
  if (tid == 0) {
    int np = 0;
    #pragma unroll
    for (int w = 0; w < 16; w++) np += s_redi[w];
    s_np = np;
  }
  __syncthreads();

  // ---- Phase 2: exact k-th-largest of ce_neg (LDS) via MSB radix select
  const int k = min(s_np * 3, Pn);
  unsigned prefix = 0, maskb = 0;
  int kk = k;
  if (k > 0) {
    for (int shift = 24; shift >= 0; shift -= 8) {
      #pragma unroll
      for (int j = 0; j < 4; j++) hist[wave][lane * 4 + j] = 0;
      __syncthreads();
      for (int i = tid; i < Pn; i += 1024) {
        unsigned u = __float_as_uint(s_ce[i]);
        if ((u & maskb) == prefix) atomicAdd(&hist[wave][(u >> shift) & 255u], 1u);
      }
      __syncthreads();
      if (tid < 256) {
        unsigned c = 0;
        #pragma unroll
        for (int w = 0; w < 16; w++) c += hist[w][tid];
        hist[0][tid] = c;
      }
      __syncthreads();
      if (tid == 0) {
        int cum = 0, chosen = 0;
        for (int bin = 255; bin >= 0; bin--) {
          int c = (int)hist[0][bin];
          if (cum + c >= kk) { chosen = bin; break; }
          cum += c;
        }
        s_prefix = prefix | ((unsigned)chosen << shift);
        s_kk = kk - cum;
      }
      __syncthreads();
      prefix = s_prefix; kk = s_kk;
      maskb |= 255u << shift;
      __syncthreads();
    }
  }
  float T = __uint_as_float(prefix);

  float sum_gt = 0.0f; int cnt_gt = 0;
  if (k > 0) {
    for (int i = tid; i < Pn; i += 1024) {
      float x = s_ce[i];
      if (x > T) { sum_gt += x; cnt_gt++; }
    }
  }
  #pragma unroll
  for (int off = 32; off; off >>= 1) {
    sum_gt += __shfl_down(sum_gt, off);
    cnt_gt += __shfl_down(cnt_gt, off);
  }
  if (lane == 0) { s_red[2][wave] = sum_gt; s_redi[wave] = cnt_gt; }
  __syncthreads();
  if (tid == 0) {
    float sg = 0.0f, ll = 0.0f, cp = 0.0f; int cg = 0;
    #pragma unroll
    for (int w = 0; w < 16; w++) {
      sg += s_red[2][w]; cg += s_redi[w];
      ll += s_red[0][w]; cp += s_red[1][w];
    }
    float sel = (k > 0) ? (sg + (float)(k - cg) * T) : 0.0f;
    blk_res[b] = make_float4(ll, cp + sel, (float)s_np, 0.0f);
  }
}

__global__ __launch_bounds__(64) void finalize_kernel(
    const float4* __restrict__ blk_res, float* __restrict__ out) {
  const int tid = threadIdx.x;
  float4 r1 = blk_res[tid];
  float4 r2 = blk_res[tid + 64];
  float ll = r1.x + r2.x, lc = r1.y + r2.y, n = r1.z + r2.z;
  #pragma unroll
  for (int off = 32; off; off >>= 1) {
    ll += __shfl_down(ll, off);
    lc += __shfl_down(lc, off);
    n  += __shfl_down(n, off);
  }
  if (tid == 0) {
    out[0] = ll / n;
    out[1] = lc / n;
  }
}

extern "C" void kernel_launch(void* const* d_in, const int* in_sizes, int n_in,
                              void* d_out, int out_size, void* d_ws, size_t ws_size,
                              hipStream_t stream) {
  const float* loc_data  = (const float*)d_in[0];
  const float* conf_data = (const float*)d_in[1];
  const float* dbox      = (const float*)d_in[2];
  const float* targets   = (const float*)d_in[3];
  float* out = (float*)d_out;
  float4* blk_res = (float4*)d_ws;   // 128 float4, fully overwritten each call

  fused_kernel<<<Bn, 1024, 0, stream>>>(loc_data, conf_data, dbox, targets, blk_res);
  finalize_kernel<<<1, 64, 0, stream>>>(blk_res, out);
}

// Round 4
// 233.141 us; speedup vs baseline: 2.1899x; 1.2106x over previous
//
#include <hip/hip_runtime.h>
#include <cstddef>

#define Bn 128
#define Pn 8732
#define Cn 21
#define On 16
#define MAGIC 0x13579BDFu

__device__ __forceinline__ void argmax_combine(float& v, int& p, float v2, int p2) {
  if (v2 > v || (v2 == v && p2 < p)) { v = v2; p = p2; }
}

// ---------------------------------------------------------------------------
// Kernel A: full-machine streaming pass over conf_data (94 MB) + IoU matching.
// 4096 waves = 128 images x 32 chunk-groups; wave w -> image (w & 127),
// chunks ci = (w>>7) + 32*i, i=0..4 (64 priors each; exactly covers 0..136).
// Barrier-free: per-wave LDS staging (coalesced float4), per-lane row compute.
// Outputs: ce0 (lse - x[0]), pack byte (bti | pos<<4), per-truth argmax keys
// via u64 atomicMax (key monotone in ov; tie -> smallest p; beats 0xAA poison).
// ---------------------------------------------------------------------------
__global__ __launch_bounds__(256) void stream_kernel(
    const float* __restrict__ conf, const float* __restrict__ dbox,
    const float* __restrict__ targets,
    float* __restrict__ ce0, unsigned char* __restrict__ pack,
    unsigned long long* __restrict__ keys) {
  const int wb = threadIdx.x >> 6, lane = threadIdx.x & 63;
  const int wave_g = blockIdx.x * 4 + wb;
  const int b = wave_g & 127;
  const int cg = wave_g >> 7;                    // 0..31

  __shared__ float4 s_row4[4][336];              // 5376 B per wave
  __shared__ float s_tt[4][On * 5];
  __shared__ float s_ar[4][On];

  if (lane < On * 5) s_tt[wb][lane] = targets[(size_t)b * On * 5 + lane];
  if (lane < On) {
    // depends on s_tt written by same wave; in-wave LDS ordering + waitcnt
    float x1 = targets[(size_t)b * On * 5 + lane * 5 + 0];
    float y1 = targets[(size_t)b * On * 5 + lane * 5 + 1];
    float x2 = targets[(size_t)b * On * 5 + lane * 5 + 2];
    float y2 = targets[(size_t)b * On * 5 + lane * 5 + 3];
    s_ar[wb][lane] = (x2 - x1) * (y2 - y1);
  }

  float bestv[On]; int bestp[On];
  #pragma unroll
  for (int j = 0; j < On; j++) { bestv[j] = -1.0f; bestp[j] = 0x7fffffff; }

  #pragma unroll
  for (int i = 0; i < 5; i++) {
    const int ci = cg + 32 * i;
    if (ci >= 137) break;
    const int p0 = ci * 64;
    const int rows = min(64, Pn - p0);           // 64 or 28 (both %4==0)
    const int n4 = rows * Cn / 4;                // 336 or 147

    const float4* src = (const float4*)(conf + ((size_t)b * Pn + p0) * Cn);
    float4 v0, v1, v2, v3, v4, v5;
    // fully unrolled, predicated, independent -> deep MLP, coalesced 1KB/instr
    if (lane < n4)        v0 = src[lane];
    if (lane + 64 < n4)   v1 = src[lane + 64];
    if (lane + 128 < n4)  v2 = src[lane + 128];
    if (lane + 192 < n4)  v3 = src[lane + 192];
    if (lane + 256 < n4)  v4 = src[lane + 256];
    if (lane + 320 < n4)  v5 = src[lane + 320];
    if (lane < n4)        s_row4[wb][lane] = v0;
    if (lane + 64 < n4)   s_row4[wb][lane + 64] = v1;
    if (lane + 128 < n4)  s_row4[wb][lane + 128] = v2;
    if (lane + 192 < n4)  s_row4[wb][lane + 192] = v3;
    if (lane + 256 < n4)  s_row4[wb][lane + 256] = v4;
    if (lane + 320 < n4)  s_row4[wb][lane + 320] = v5;

    if (lane < rows) {
      const int p = p0 + lane;
      const float* x = (const float*)s_row4[wb] + lane * Cn;  // stride 21: 2-way, free
      float m = x[0];
      #pragma unroll
      for (int q = 1; q < Cn; q++) m = fmaxf(m, x[q]);
      float s = 0.0f;
      #pragma unroll
      for (int q = 0; q < Cn; q++) s += expf(x[q] - m);
      float lse = m + logf(s);
      ce0[(size_t)b * Pn + p] = lse - x[0];

      float4 d = ((const float4*)dbox)[p];
      float px1 = d.x - d.z * 0.5f, py1 = d.y - d.w * 0.5f;
      float px2 = d.x + d.z * 0.5f, py2 = d.y + d.w * 0.5f;
      float ap = d.z * d.w;
      float mv = -1.0f; int mj = 0;
      #pragma unroll
      for (int j = 0; j < On; j++) {
        float lx = fmaxf(s_tt[wb][j*5+0], px1);
        float ly = fmaxf(s_tt[wb][j*5+1], py1);
        float rx = fminf(s_tt[wb][j*5+2], px2);
        float ry = fminf(s_tt[wb][j*5+3], py2);
        float w = fmaxf(rx - lx, 0.0f), h = fmaxf(ry - ly, 0.0f);
        float inter = w * h;
        float ov = inter / (s_ar[wb][j] + ap - inter);
        if (ov > bestv[j]) { bestv[j] = ov; bestp[j] = p; }  // smallest p kept
        if (ov > mv) { mv = ov; mj = j; }                    // first max over j
      }
      pack[(size_t)b * Pn + p] =
          (unsigned char)(mj | ((mv >= 0.5f) ? 16 : 0));
    }
  }

  // per-truth argmax: wave shuffle reduce, then device atomicMax
  #pragma unroll
  for (int j = 0; j < On; j++) {
    float v = bestv[j]; int p = bestp[j];
    #pragma unroll
    for (int off = 32; off; off >>= 1) {
      float v2 = __shfl_down(v, off);
      int p2 = __shfl_down(p, off);
      argmax_combine(v, p, v2, p2);
    }
    if (lane == 0) {
      unsigned long long key;
      if (v < 0.0f) key = 0xC000000000000000ull;   // neutral, still beats poison
      else key = (((unsigned long long)(__float_as_uint(v) | 0xC0000000u)) << 32)
               | (unsigned long long)(0xFFFFFFFFu - (unsigned)p);
      atomicMax(&keys[b * On + j], key);
    }
  }
}

// ---------------------------------------------------------------------------
// Kernel B: per-image (128 blocks x 1024): forced matches, losses, register-
// based exact radix top-k, flag-based cross-block reduction (no extra node).
// ---------------------------------------------------------------------------
__global__ __launch_bounds__(1024) void reduce_kernel(
    const float* __restrict__ loc, const float* __restrict__ conf,
    const float* __restrict__ dbox, const float* __restrict__ targets,
    const float* __restrict__ ce0, const unsigned char* __restrict__ pack,
    const unsigned long long* __restrict__ keys,
    unsigned int* __restrict__ res, float* __restrict__ out) {
  const int b = blockIdx.x;
  const int tid = threadIdx.x;
  const int wave = tid >> 6, lane = tid & 63;

  __shared__ float s_t[On * 5];
  __shared__ int s_bp[On];
  __shared__ unsigned hist[16][256];
  __shared__ float s_redf[2][16];
  __shared__ int s_redi[16];
  __shared__ unsigned s_prefix;
  __shared__ int s_kk;
  __shared__ int s_np;

  if (tid < On * 5) s_t[tid] = targets[(size_t)b * On * 5 + tid];
  if (tid < On)
    s_bp[tid] = (int)(0xFFFFFFFFu - (unsigned)(keys[b * On + tid] & 0xFFFFFFFFull));
  __syncthreads();

  float ce_r[9];
  float my_loc = 0.0f, my_cep = 0.0f; int my_np = 0;
  #pragma unroll
  for (int sI = 0; sI < 9; sI++) {
    ce_r[sI] = 0.0f;
    const int p = tid + 1024 * sI;
    if (p < Pn) {
      unsigned char pk = pack[(size_t)b * Pn + p];
      float c0 = ce0[(size_t)b * Pn + p];
      int pos = pk >> 4;
      int bt = pk & 15;
      #pragma unroll
      for (int j = 0; j < On; j++)
        if (s_bp[j] == p) { bt = j; pos = 1; }      // ascending: last j wins
      ce_r[sI] = pos ? 0.0f : c0;
      if (pos) {
        my_np++;
        const float* t = &s_t[bt * 5];
        int c = (int)t[4] + 1;
        const float* row = conf + ((size_t)b * Pn + p) * Cn;
        my_cep += c0 + row[0] - row[c];             // lse - x[c]
        float4 d = ((const float4*)dbox)[p];
        float mx1 = t[0], my1 = t[1], mx2 = t[2], my2 = t[3];
        float g0 = ((mx1 + mx2) * 0.5f - d.x) / (0.1f * d.z);
        float g1 = ((my1 + my2) * 0.5f - d.y) / (0.1f * d.w);
        float g2 = logf((mx2 - mx1) / d.z) / 0.2f;
        float g3 = logf((my2 - my1) / d.w) / 0.2f;
        float4 ld = ((const float4*)loc)[(size_t)b * Pn + p];
        float g[4] = {g0, g1, g2, g3};
        float l[4] = {ld.x, ld.y, ld.z, ld.w};
        #pragma unroll
        for (int q = 0; q < 4; q++) {
          float ad = fabsf(l[q] - g[q]);
          my_loc += (ad < 1.0f) ? 0.5f * ad * ad : ad - 0.5f;
        }
      }
    }
  }

  {
    int np = my_np;
    #pragma unroll
    for (int off = 32; off; off >>= 1) np += __shfl_down(np, off);
    if (lane == 0) s_redi[wave] = np;
  }
  __syncthreads();
  if (tid == 0) {
    int np = 0;
    #pragma unroll
    for (int w = 0; w < 16; w++) np += s_redi[w];
    s_np = np;
  }
  __syncthreads();

  // exact k-th largest over register ce_neg values (all >= 0)
  const int k = min(s_np * 3, Pn);
  unsigned prefix = 0, maskb = 0;
  int kk = k;
  for (int shift = 24; shift >= 0; shift -= 8) {
    #pragma unroll
    for (int j = 0; j < 4; j++) hist[wave][lane * 4 + j] = 0;
    __syncthreads();
    #pragma unroll
    for (int sI = 0; sI < 9; sI++) {
      const int p = tid + 1024 * sI;
      if (p < Pn) {
        unsigned u = __float_as_uint(ce_r[sI]);
        if ((u & maskb) == prefix) atomicAdd(&hist[wave][(u >> shift) & 255u], 1u);
      }
    }
    __syncthreads();
    if (tid < 256) {
      unsigned c = 0;
      #pragma unroll
      for (int w = 0; w < 16; w++) c += hist[w][tid];
      hist[0][tid] = c;
    }
    __syncthreads();
    if (tid == 0) {
      int cum = 0, chosen = 0;
      for (int bin = 255; bin >= 0; bin--) {
        int c = (int)hist[0][bin];
        if (cum + c >= kk) { chosen = bin; break; }
        cum += c;
      }
      s_prefix = prefix | ((unsigned)chosen << shift);
      s_kk = kk - cum;
    }
    __syncthreads();
    prefix = s_prefix; kk = s_kk;
    maskb |= 255u << shift;
    __syncthreads();
  }
  float T = __uint_as_float(prefix);

  float sum_gt = 0.0f; int cnt_gt = 0;
  #pragma unroll
  for (int sI = 0; sI < 9; sI++) {
    const int p = tid + 1024 * sI;
    if (p < Pn) {
      float x = ce_r[sI];
      if (x > T) { sum_gt += x; cnt_gt++; }
    }
  }
  #pragma unroll
  for (int off = 32; off; off >>= 1) {
    sum_gt += __shfl_down(sum_gt, off);
    cnt_gt += __shfl_down(cnt_gt, off);
    my_loc += __shfl_down(my_loc, off);
    my_cep += __shfl_down(my_cep, off);
  }
  if (lane == 0) {
    s_redf[0][wave] = my_loc; s_redf[1][wave] = sum_gt + my_cep; s_redi[wave] = cnt_gt;
  }
  __syncthreads();
  if (tid == 0) {
    float ll = 0.0f, lc = 0.0f; int cg = 0;
    #pragma unroll
    for (int w = 0; w < 16; w++) {
      ll += s_redf[0][w]; lc += s_redf[1][w]; cg += s_redi[w];
    }
    lc += (k > 0) ? (float)(k - cg) * T : 0.0f;
    // post partials (device-scope atomics; visible cross-XCD), then flag
    atomicExch(&res[b * 4 + 0], __float_as_uint(ll));
    atomicExch(&res[b * 4 + 1], __float_as_uint(lc));
    atomicExch(&res[b * 4 + 2], (unsigned)s_np);
    __threadfence();
    atomicExch(&res[b * 4 + 3], MAGIC);
  }

  // block 0, wave 0: gather all 128 partials and finalize (no extra kernel)
  if (b == 0 && tid < 64) {
    float ll = 0.0f, lc = 0.0f; int np = 0;
    #pragma unroll
    for (int h = 0; h < 2; h++) {
      const int i = tid + 64 * h;
      while (atomicAdd(&res[i * 4 + 3], 0u) != MAGIC) { __builtin_amdgcn_s_sleep(8); }
      ll += __uint_as_float(atomicAdd(&res[i * 4 + 0], 0u));
      lc += __uint_as_float(atomicAdd(&res[i * 4 + 1], 0u));
      np += (int)atomicAdd(&res[i * 4 + 2], 0u);
    }
    #pragma unroll
    for (int off = 32; off; off >>= 1) {
      ll += __shfl_down(ll, off);
      lc += __shfl_down(lc, off);
      np += __shfl_down(np, off);
    }
    if (tid == 0) {
      float fN = (float)np;
      out[0] = ll / fN;
      out[1] = lc / fN;
    }
  }
}

extern "C" void kernel_launch(void* const* d_in, const int* in_sizes, int n_in,
                              void* d_out, int out_size, void* d_ws, size_t ws_size,
                              hipStream_t stream) {
  const float* loc_data  = (const float*)d_in[0];
  const float* conf_data = (const float*)d_in[1];
  const float* dbox      = (const float*)d_in[2];
  const float* targets   = (const float*)d_in[3];
  float* out = (float*)d_out;

  char* ws = (char*)d_ws;
  float* ce0 = (float*)ws;                                           // B*P f32
  unsigned char* pack = (unsigned char*)(ws + (size_t)Bn * Pn * 4);  // B*P bytes
  unsigned long long* keys =
      (unsigned long long*)(ws + (size_t)Bn * Pn * 5);               // B*16 u64
  unsigned int* res = (unsigned int*)(ws + (size_t)Bn * Pn * 5 + Bn * On * 8); // B*4 u32

  stream_kernel<<<1024, 256, 0, stream>>>(conf_data, dbox, targets, ce0, pack, keys);
  reduce_kernel<<<Bn, 1024, 0, stream>>>(loc_data, conf_data, dbox, targets,
                                         ce0, pack, keys, res, out);
}